// Round 6
// baseline (5010.414 us; speedup 1.0000x reference)
//
#include <hip/hip_runtime.h>

typedef __attribute__((ext_vector_type(8))) short bf16x8;
typedef __attribute__((ext_vector_type(4))) float floatx4;
typedef __attribute__((ext_vector_type(4))) unsigned int uintx4;

#define EPSF 1e-5f
#define RS512 0.04419417382415922f /* 1/sqrt(512) */

__device__ __forceinline__ unsigned short f2bf(float f) {
  unsigned int u = __float_as_uint(f);
  u += 0x7fffu + ((u >> 16) & 1u);
  return (unsigned short)(u >> 16);
}

union BFrag { bf16x8 v; int i[4]; unsigned short s[8]; };

// async global -> LDS, 16B per lane. LDS dest is wave-uniform base + lane*16;
// global src is per-lane (lets us swizzle V's placement at the source).
__device__ __forceinline__ void gll16(const void* g, void* l) {
  __builtin_amdgcn_global_load_lds(
      (__attribute__((address_space(1))) void*)g,
      (__attribute__((address_space(3))) void*)l, 16, 0, 0);
}

// ---------------- Kernel 1: MFMA qkv conv + BN + PReLU, bf16 emit -----------
// Split-precision W (bf16 hi + residual lo), two chained MFMAs, f32 accum.
// LDS trimmed to 51.9 KB -> 3 blocks/CU (6 waves/SIMD) for latency hiding.
// Q: [8][4000][512] token-major; K: same (pre-scaled 1/sqrt(512));
// V: tiled [8][125][512][32].
__global__ __launch_bounds__(512) void qkv_kernel(
    const float* __restrict__ x,
    const float* __restrict__ Wq, const float* __restrict__ bq,
    const float* __restrict__ gq, const float* __restrict__ beq,
    const float* __restrict__ mq, const float* __restrict__ vq,
    const float* __restrict__ aq,
    unsigned short* __restrict__ Q, unsigned short* __restrict__ K,
    unsigned short* __restrict__ V) {
  const int b = blockIdx.y;
  const int t0 = blockIdx.x << 4;  // 250 blocks: t0 in [0,4000)
  const int tid = threadIdx.x;

  // smem map (compute): xs2 bf16 [f=32][t=16][c pitch 40] @0 (41472 B),
  //   sWA bf16 [6][64][8] @41472 (6144 B).
  // epilogue overlay: oQ [16][520] @0, oK @16640 B, oV [512][18] @33280 B
  // (ends 51712). sWA sits inside oV's range but is consumed into registers
  // before the epilogue barrier.
  __shared__ __align__(16) unsigned char smem[51712];
  unsigned short* xs2 = (unsigned short*)smem;
  unsigned short* sWA = (unsigned short*)(smem + 41472);
  __shared__ float sB[48];

  // ---- phase 1: build split-precision A fragments + bias; stage x tile ----
  for (int a = tid; a < 3072; a += 512) {
    int j = a & 7, l = (a >> 3) & 63, slot = a >> 9;
    int n = slot >> 1, hl = slot & 1;
    int ch = l & 15, cc = ((l >> 4) << 3) + j;
    float inv = gq[n * 16 + ch] * rsqrtf(vq[n * 16 + ch] + EPSF);
    if (n == 1) inv *= RS512;
    float wf = Wq[(n * 16 + ch) * 32 + cc] * inv;
    unsigned short hi = f2bf(wf);
    if (hl) {
      float hif = __uint_as_float((unsigned int)hi << 16);
      sWA[a] = f2bf(wf - hif);
    } else {
      sWA[a] = hi;
    }
  }
  if (tid < 48) {
    int n = tid >> 4;
    float inv = gq[tid] * rsqrtf(vq[tid] + EPSF);
    float bb = (bq[tid] - mq[tid]) * inv + beq[tid];
    if (n == 1) bb *= RS512;
    sB[tid] = bb;
  }
  {  // x[b, c, f, t0..t0+15] -> xs2[f][t][c], float4 over t
    int tq = tid & 3, rq = tid >> 2;
    const float* xb = x + (size_t)b * 1024 * 4000 + t0 + (tq << 2);
    for (int rr = rq; rr < 1024; rr += 128) {
      float4 f = *(const float4*)(xb + (size_t)rr * 4000);
      const int cc = rr >> 5, fch = rr & 31;
      unsigned short* dst = xs2 + fch * 648 + (tq << 2) * 40 + cc;
      dst[0] = f2bf(f.x);
      dst[40] = f2bf(f.y);
      dst[80] = f2bf(f.z);
      dst[120] = f2bf(f.w);
    }
  }
  __syncthreads();

  // ---- phase 2: MFMA compute ----
  const int lane = tid & 63, w = tid >> 6;
  const int tl = lane & 15, qd = lane >> 4;
  const float aQ = aq[0], aK = aq[1], aV = aq[2];

  bf16x8 Af[3][2];
#pragma unroll
  for (int n = 0; n < 3; ++n)
#pragma unroll
    for (int hl = 0; hl < 2; ++hl)
      Af[n][hl] = *(const bf16x8*)(sWA + ((((n << 1) + hl) << 6) + lane) * 8);

  floatx4 acc[3][4];
#pragma unroll
  for (int n = 0; n < 3; ++n)
#pragma unroll
    for (int ff = 0; ff < 4; ++ff) {
      acc[n][ff][0] = 0.f; acc[n][ff][1] = 0.f;
      acc[n][ff][2] = 0.f; acc[n][ff][3] = 0.f;
    }

#pragma unroll
  for (int ff = 0; ff < 4; ++ff) {
    const int f = (w << 2) + ff;
    bf16x8 xb = *(const bf16x8*)(xs2 + f * 648 + tl * 40 + (qd << 3));
#pragma unroll
    for (int n = 0; n < 3; ++n) {
      acc[n][ff] = __builtin_amdgcn_mfma_f32_16x16x32_bf16(Af[n][0], xb, acc[n][ff], 0, 0, 0);
      acc[n][ff] = __builtin_amdgcn_mfma_f32_16x16x32_bf16(Af[n][1], xb, acc[n][ff], 0, 0, 0);
    }
  }
  __syncthreads();  // done reading xs2/sWA -> overlay out-staging

  // ---- epilogue: bias + PReLU + bf16, transpose via LDS, coalesced store ---
  unsigned short* oQ = (unsigned short*)smem;     // [16 t][520]
  unsigned short* oK = oQ + 16 * 520;             // [16 t][520]
  unsigned short* oV = oK + 16 * 520;             // [512 d][18]
#pragma unroll
  for (int n = 0; n < 3; ++n) {
    const float sl = (n == 0) ? aQ : ((n == 1) ? aK : aV);
#pragma unroll
    for (int ff = 0; ff < 4; ++ff) {
      const int f = (w << 2) + ff;
#pragma unroll
      for (int rr = 0; rr < 4; ++rr) {
        const int ch = (qd << 2) + rr;
        float v = acc[n][ff][rr] + sB[n * 16 + ch];
        v = v > 0.f ? v : sl * v;
        unsigned short us = f2bf(v);
        const int d = (ch << 5) + f;
        if (n == 0) oQ[tl * 520 + d] = us;
        else if (n == 1) oK[tl * 520 + d] = us;
        else oV[d * 18 + tl] = us;
      }
    }
  }
  __syncthreads();

  for (int i = tid; i < 1024; i += 512) {  // Q,K: 16B-coalesced
    int t = i >> 6, u = i & 63;
    *(uintx4*)(Q + (size_t)(b * 4000 + t0 + t) * 512 + u * 8) =
        *(const uintx4*)(oQ + t * 520 + u * 8);
    *(uintx4*)(K + (size_t)(b * 4000 + t0 + t) * 512 + u * 8) =
        *(const uintx4*)(oK + t * 520 + u * 8);
  }
  {
    const int st = t0 >> 5;
    const int toff = t0 & 16;
    unsigned short* vt = V + ((size_t)(b * 125 + st) * 512) * 32 + toff;
    for (int i = tid; i < 4096; i += 512) {
      int d = i >> 3, u = i & 7;
      unsigned int w2 = *(unsigned int*)&oV[d * 18 + 2 * u];
      ((unsigned int*)(vt + d * 32))[u] = w2;
    }
  }
}

// ---------------- Kernel 2: LDS-staged sigmoid-attention + enc ConvBlock ----
// R3 compute structure (8 waves x 16q S-phase, d-split PV), but SINGLE-
// buffered K and V: LDS 76288 B -> 2 blocks/CU (4 waves/SIMD, was 2).
// Choreography: stage V_it during S (S reads only Ks), stage K_{it+1} during
// PV (PV reads only Vs+Pb); 2 barriers/iter, loads always in flight across a
// compute phase. Epilogue exchange in 4 rounds of 32 q via Eb[32][516] (66 KB
// overlay on Ks+Vs), all 8 waves active per round (o-split x4, q-half x2).
__global__ __launch_bounds__(512, 4) void attn_kernel(
    const float* __restrict__ x,
    const float* __restrict__ encW, const float* __restrict__ encb,
    const float* __restrict__ encg, const float* __restrict__ encbe,
    const float* __restrict__ encm, const float* __restrict__ encv,
    const float* __restrict__ enca,
    const unsigned short* __restrict__ Q, const unsigned short* __restrict__ K,
    const unsigned short* __restrict__ V, float* __restrict__ out) {
  const int tid = threadIdx.x;
  const int lane = tid & 63;
  const int w = tid >> 6;
  const int b = blockIdx.x >> 5;           // 8 b * 32 blocks
  const int bt0 = (blockIdx.x & 31) << 7;  // 0..3968
  const int t0 = bt0 + (w << 4);
  const bool active = t0 < 4000;
  const int c = lane & 15, qd = lane >> 4;

  // LDS map: Ks[32][520] @0 (33280 B) | Vs[512][32] @33280 (32768 B,
  // granule-permuted) | Pb[128][40] @66048 (10240 B) = 76288 B total.
  // Eb f32[32][516] (66048 B) overlays exactly Ks+Vs after the tile loop.
  __shared__ __align__(16) unsigned char smem[76288];
  unsigned short* Ksb = (unsigned short*)smem;
  unsigned short* Vsb = Ksb + 16640;
  unsigned short* Pb = Vsb + 16384;
  float* Eb = (float*)smem;

  // zero P rows once (covers q-groups of inactive tail waves)
  for (int i = tid; i < 2560; i += 512) ((unsigned int*)Pb)[i] = 0u;

  // Q fragments for this wave's 16 tokens (B operand of S-mfma)
  bf16x8 qf[16];
  {
    const int tq = active ? t0 : 0;
    const unsigned short* qp = Q + (size_t)(b * 4000 + tq + c) * 512 + qd * 8;
#pragma unroll
    for (int ks = 0; ks < 16; ++ks) qf[ks] = *(const bf16x8*)(qp + ks * 32);
  }

  floatx4 acc[4][8];  // [md within slice][q-sub]
#pragma unroll
  for (int m = 0; m < 4; ++m)
#pragma unroll
    for (int q2 = 0; q2 < 8; ++q2) {
      acc[m][q2][0] = 0.f; acc[m][q2][1] = 0.f;
      acc[m][q2][2] = 0.f; acc[m][q2][3] = 0.f;
    }

  const unsigned short* Kb = K + (size_t)b * 4000 * 512;
  const unsigned short* Vb = V + (size_t)b * 125 * 16384;

  // wave w stages K rows 4w..4w+3 (1024 B each) and V chunks 4w..4w+3
  const int r0 = w << 2;
  const int lby = lane * 8;  // 16B per lane, in shorts
  // V source swizzle (verified R1/R2): phys granule l sources logical
  // l ^ (((l>>2)&7) ^ ((l>>4)&1)); read side uses logical^((logical>>2)&7).
  const int vmask = ((lane >> 2) & 7) ^ ((lane >> 4) & 1);
  const int vsw = (lane ^ vmask) << 3;  // shorts within 1024B chunk

  auto stageK = [&](int it) {
#pragma unroll
    for (int r = 0; r < 4; ++r)
      gll16(Kb + (size_t)it * 16384 + (size_t)((r0 + r) << 9) + lby,
            Ksb + (r0 + r) * 520);
  };
  auto stageV = [&](int it) {
#pragma unroll
    for (int r = 0; r < 4; ++r)
      gll16(Vb + (size_t)it * 16384 + (size_t)((r0 + r) << 9) + vsw,
            Vsb + ((r0 + r) << 9));
  };

  stageK(0);

#pragma unroll 1
  for (int it = 0; it < 125; ++it) {
    asm volatile("s_waitcnt vmcnt(0)" ::: "memory");  // K_it landed
    __syncthreads();  // B1: PV_{it-1} done reading Vs+Pb; K_it visible
    stageV(it);       // V_it in flight across the S-phase

    if (active) {  // ---- S-phase: S = K·Q^T for own 16 q, full 32 s ----
      floatx4 sa0, sa1;
      sa0[0] = sa0[1] = sa0[2] = sa0[3] = 0.f;
      sa1 = sa0;
      const unsigned short* kp = Ksb + c * 520 + qd * 8;
      __builtin_amdgcn_s_setprio(1);
#pragma unroll
      for (int ks = 0; ks < 16; ++ks) {
        bf16x8 k0 = *(const bf16x8*)(kp + ks * 32);
        bf16x8 k1 = *(const bf16x8*)(kp + 16 * 520 + ks * 32);
        sa0 = __builtin_amdgcn_mfma_f32_16x16x32_bf16(k0, qf[ks], sa0, 0, 0, 0);
        sa1 = __builtin_amdgcn_mfma_f32_16x16x32_bf16(k1, qf[ks], sa1, 0, 0, 0);
      }
      __builtin_amdgcn_s_setprio(0);
      // sigmoid -> packed bf16 -> P[q = w*16+c][s] (lane holds s = qd*4+r, +16)
      float p0 = __builtin_amdgcn_rcpf(1.f + __expf(-sa0[0]));
      float p1 = __builtin_amdgcn_rcpf(1.f + __expf(-sa0[1]));
      float p2 = __builtin_amdgcn_rcpf(1.f + __expf(-sa0[2]));
      float p3 = __builtin_amdgcn_rcpf(1.f + __expf(-sa0[3]));
      float p4 = __builtin_amdgcn_rcpf(1.f + __expf(-sa1[0]));
      float p5 = __builtin_amdgcn_rcpf(1.f + __expf(-sa1[1]));
      float p6 = __builtin_amdgcn_rcpf(1.f + __expf(-sa1[2]));
      float p7 = __builtin_amdgcn_rcpf(1.f + __expf(-sa1[3]));
      unsigned short* pw = Pb + ((w << 4) + c) * 40 + (qd << 2);
      uint2 pa, pb2;
      pa.x = (unsigned int)f2bf(p0) | ((unsigned int)f2bf(p1) << 16);
      pa.y = (unsigned int)f2bf(p2) | ((unsigned int)f2bf(p3) << 16);
      pb2.x = (unsigned int)f2bf(p4) | ((unsigned int)f2bf(p5) << 16);
      pb2.y = (unsigned int)f2bf(p6) | ((unsigned int)f2bf(p7) << 16);
      *(uint2*)pw = pa;
      *(uint2*)(pw + 16) = pb2;
    }

    asm volatile("s_waitcnt vmcnt(0)" ::: "memory");  // V_it landed
    __syncthreads();  // B2: P complete; S done reading Ks
    if (it + 1 < 125) stageK(it + 1);  // K_{it+1} in flight across PV

    {  // ---- PV-phase (ALL waves): d-slice [64w,64w+64) for all 128 q ----
      const unsigned short* vp = Vsb + ((((c << 2) | qd) ^ (c & 7)) << 3);
      bf16x8 vf[4];
#pragma unroll
      for (int m = 0; m < 4; ++m)
        vf[m] = *(const bf16x8*)(vp + ((r0 + m) << 9));
      __builtin_amdgcn_s_setprio(1);
#pragma unroll
      for (int h = 0; h < 2; ++h) {
        bf16x8 pf[4];
#pragma unroll
        for (int q2 = 0; q2 < 4; ++q2)
          pf[q2] = *(const bf16x8*)(Pb + ((((h << 2) | q2) << 4) + c) * 40 +
                                    (qd << 3));
#pragma unroll
        for (int m = 0; m < 4; ++m)
#pragma unroll
          for (int q2 = 0; q2 < 4; ++q2)
            acc[m][(h << 2) | q2] = __builtin_amdgcn_mfma_f32_16x16x32_bf16(
                vf[m], pf[q2], acc[m][(h << 2) | q2], 0, 0, 0);
      }
      __builtin_amdgcn_s_setprio(0);
    }
  }

  __syncthreads();  // all K/V/P reads done -> Eb may overlay Ks+Vs

  // ---- epilogue: 4 rounds of 32 q via Eb; all 8 waves active per round ----
  const float ealpha = enca[0];
#pragma unroll 1
  for (int r = 0; r < 4; ++r) {
#pragma unroll
    for (int qq = 0; qq < 2; ++qq)
#pragma unroll
      for (int m = 0; m < 4; ++m)
        *(floatx4*)&Eb[((qq << 4) + c) * 516 + (w << 6) + (m << 4) +
                       (qd << 2)] = acc[m][(r << 1) | qq];
    __syncthreads();
    {
      const int h = w & 1, og = w >> 1;  // q-half within 32, o-group of 8
      const int tq = bt0 + (r << 5) + (h << 4);
      if (tq < 4000) {
        const float* er = Eb + ((h << 4) + c) * 516;
#pragma unroll
        for (int hi = 0; hi < 2; ++hi) {
          floatx4 sh[16];
#pragma unroll
          for (int i = 0; i < 16; ++i)
            sh[i] = *(const floatx4*)&er[(i << 5) + (hi << 4) + (qd << 2)];
#pragma unroll 1
          for (int oo = 0; oo < 8; ++oo) {
            const int o = (og << 3) + oo;
            float inv = encg[o] * rsqrtf(encv[o] + EPSF);
            float bfo = (encb[o] - encm[o]) * inv + encbe[o];
            float e0 = 0.f, e1 = 0.f, e2 = 0.f, e3 = 0.f;
#pragma unroll
            for (int i = 0; i < 16; ++i) {
              float wi = encW[(o << 4) + i];
              e0 += wi * sh[i][0]; e1 += wi * sh[i][1];
              e2 += wi * sh[i][2]; e3 += wi * sh[i][3];
            }
            float ee[4] = {e0, e1, e2, e3};
#pragma unroll
            for (int rr = 0; rr < 4; ++rr) {
              float e = ee[rr] * inv + bfo;
              e = e > 0.f ? e : ealpha * e;
              int fq = (qd << 2) + rr + (hi << 4);
              size_t idx = ((size_t)((b << 5) + o) * 32 + fq) * 4000 + tq + c;
              out[idx] = e + x[idx];
            }
          }
        }
      }
    }
    __syncthreads();
  }
}

extern "C" void kernel_launch(void* const* d_in, const int* in_sizes, int n_in,
                              void* d_out, int out_size, void* d_ws,
                              size_t ws_size, hipStream_t stream) {
  const float* x = (const float*)d_in[0];
  unsigned short* Q = (unsigned short*)d_ws;
  unsigned short* K = Q + (size_t)8 * 4000 * 512;
  unsigned short* V = K + (size_t)8 * 4000 * 512;

  dim3 g1(250, 8);
  qkv_kernel<<<g1, 512, 0, stream>>>(
      x, (const float*)d_in[1], (const float*)d_in[2], (const float*)d_in[3],
      (const float*)d_in[4], (const float*)d_in[5], (const float*)d_in[6],
      (const float*)d_in[7], Q, K, V);

  attn_kernel<<<dim3(256), 512, 0, stream>>>(
      x, (const float*)d_in[8], (const float*)d_in[9], (const float*)d_in[10],
      (const float*)d_in[11], (const float*)d_in[12], (const float*)d_in[13],
      (const float*)d_in[14], Q, K, V, (float*)d_out);
}